// Round 12
// baseline (135.970 us; speedup 1.0000x reference)
//
#include <hip/hip_runtime.h>
#include <stdint.h>

#define K_ANCH 131072
#define G_BOX  256
#define NPOS_TGT 128
#define NSAMPLE 256
#define POS_CAP 8192
#define NEG_CAP 32768
#define NPART 16

// ---------------- Threefry-2x32-20 (JAX-compatible) ----------------
struct TF2 { uint32_t a, b; };

__host__ __device__ constexpr uint32_t rotl32(uint32_t v, int d) {
  return (v << d) | (v >> (32 - d));
}

__host__ __device__ constexpr TF2 threefry(uint32_t k0, uint32_t k1,
                                           uint32_t x0, uint32_t x1) {
  const uint32_t ks0 = k0, ks1 = k1, ks2 = k0 ^ k1 ^ 0x1BD11BDAu;
  const int R0[4] = {13, 15, 26, 6};
  const int R1[4] = {17, 29, 16, 24};
  x0 += ks0; x1 += ks1;
  for (int r = 0; r < 4; ++r) { x0 += x1; x1 = rotl32(x1, R0[r]); x1 ^= x0; }
  x0 += ks1; x1 += ks2 + 1u;
  for (int r = 0; r < 4; ++r) { x0 += x1; x1 = rotl32(x1, R1[r]); x1 ^= x0; }
  x0 += ks2; x1 += ks0 + 2u;
  for (int r = 0; r < 4; ++r) { x0 += x1; x1 = rotl32(x1, R0[r]); x1 ^= x0; }
  x0 += ks0; x1 += ks1 + 3u;
  for (int r = 0; r < 4; ++r) { x0 += x1; x1 = rotl32(x1, R1[r]); x1 ^= x0; }
  x0 += ks1; x1 += ks2 + 4u;
  for (int r = 0; r < 4; ++r) { x0 += x1; x1 = rotl32(x1, R0[r]); x1 ^= x0; }
  x0 += ks2; x1 += ks0 + 5u;
  return TF2{x0, x1};
}

constexpr TF2 KPOS = threefry(0u, 42u, 0u, 0u);  // k1 -> p_pos
constexpr TF2 KNEG = threefry(0u, 42u, 0u, 1u);  // k2 -> p_neg

__device__ __forceinline__ uint32_t rbits(TF2 k, uint32_t i) {
  TF2 r = threefry(k.a, k.b, 0u, i);
  return r.a ^ r.b;
}

__device__ __forceinline__ float p_from_bits(uint32_t bits) {
  uint32_t fb = 0x3f800000u | (bits >> 9);
  float f = __uint_as_float(fb) - 1.0f;
  return fmaxf(f, 0.0f);
}

__device__ __forceinline__ uint64_t prio_key(float p, uint32_t idx) {
  return ((uint64_t)__float_as_uint(p) << 32) | (uint64_t)idx;
}

// IoU bitwise-matched to reference (contract off, select-form inter -> always +0)
__device__ __forceinline__ uint32_t iou_bits(float4 a, float area_a, float4 b, float ab) {
  #pragma clang fp contract(off)
  float tlx = fmaxf(a.x, b.x), tly = fmaxf(a.y, b.y);
  float brx = fminf(a.z, b.z), bry = fminf(a.w, b.w);
  float w = brx - tlx, h = bry - tly;
  float wh = w * h;
  bool ok = (tlx < brx) && (tly < bry);
  float inter = ok ? wh : 0.0f;
  float u = (area_a + ab) - inter;
  float v = inter / u;                // IEEE div, v >= +0
  return __float_as_uint(v);
}

struct ScalarBlk {
  unsigned long long cutoff[2];
  int B_pos, r_pos, B_neg, r_neg;
  int do_pos, do_neg, pos_kept, pad;
};

// K1 (fused, small-tile): block = 64 anchors x 256 gts, 2048 blocks.
// 4 rounds of 64 gts: phase1 fills [64 cols][65] tile (16.6 KB) while keeping
// per-anchor argmax in registers; phase2 = all 256 threads scan (col, 16-anchor
// segment); 64 threads merge segments. Zero cross-lane ops; ~26 KB LDS total
// -> 6 blocks/CU = 24 waves/CU (R11's 40 KB tile capped us at 3 blocks/CU).
__global__ __launch_bounds__(256) void k_fused(const float4* __restrict__ anchor,
                                               const float4* __restrict__ bbox,
                                               int* __restrict__ argmax,
                                               int* __restrict__ label,
                                               unsigned long long* __restrict__ gkey_part) {
  __shared__ float4 gts[G_BOX];             // 4 KB
  __shared__ float gab[G_BOX];              // 1 KB (bitwise-same area_b products)
  __shared__ uint32_t tile[64 * 65];        // 16.6 KB, pad 65 -> conflict-free
  __shared__ uint32_t pb[4 * 64];           // 1 KB per-segment partial best
  __shared__ int pi_[4 * 64];               // 1 KB per-segment partial argmax
  __shared__ uint32_t xb[4][64];            // 1 KB per-quarter per-anchor best
  __shared__ int xi[4][64];                 // 1 KB
  int tid = threadIdx.x;
  int al = tid & 63, q = tid >> 6;
  int abase = blockIdx.x * 64;
  int i = abase + al;

  float4 bbv = bbox[tid];
  gts[tid] = bbv;
  {
    #pragma clang fp contract(off)
    gab[tid] = (bbv.z - bbv.x) * (bbv.w - bbv.y);
  }
  __syncthreads();

  float4 a = anchor[i];
  float area_a;
  {
    #pragma clang fp contract(off)
    area_a = (a.z - a.x) * (a.w - a.y);
  }
  uint32_t bestbits = 0u; int bidx = 0;     // iou>=+0 -> u32 cmp == f32 cmp

  int col2 = tid & 63, seg = tid >> 6;      // phase2 ownership
  #pragma unroll
  for (int r = 0; r < 4; ++r) {
    int rbase = r * 64;
    // phase1: thread (al,q) computes cols c = q*16+[0,16) of this round
    #pragma unroll
    for (int s = 0; s < 16; ++s) {
      int c = q * 16 + s;
      int g = rbase + c;
      float4 b = gts[g];                    // broadcast ds_read_b128
      float ab = gab[g];
      uint32_t vb = iou_bits(a, area_a, b, ab);
      if (vb > bestbits) { bestbits = vb; bidx = g; }  // ascending g per thread
      tile[c * 65 + al] = vb;               // lanes consecutive -> conflict-free
    }
    __syncthreads();                        // tile complete (also orders prev merge)
    // phase2: all 256 threads: scan 16 anchors of one column
    {
      int a0 = seg * 16;
      uint32_t cb = tile[col2 * 65 + a0]; int ca = a0;
      #pragma unroll
      for (int aa = 1; aa < 16; ++aa) {
        uint32_t v = tile[col2 * 65 + a0 + aa];   // stride-65 -> 2-way = free
        if (v > cb) { cb = v; ca = a0 + aa; }     // first-max within segment
      }
      pb[seg * 64 + col2] = cb; pi_[seg * 64 + col2] = ca;
    }
    __syncthreads();                        // partials ready
    // merge 4 segments (ascending seg = ascending anchor; strict > keeps first)
    if (tid < 64) {
      uint32_t cb = pb[tid]; int ca = pi_[tid];
      #pragma unroll
      for (int sg = 1; sg < 4; ++sg) {
        uint32_t v = pb[sg * 64 + tid];
        if (v > cb) { cb = v; ca = pi_[sg * 64 + tid]; }
      }
      unsigned long long key =
          ((unsigned long long)cb << 32) |
          (unsigned long long)(~(uint32_t)(abase + ca));
      atomicMax(&gkey_part[(blockIdx.x & (NPART - 1)) * G_BOX + rbase + tid], key);
    }
    // next round's phase1 sync orders this merge before pb/pi_ overwrite
  }

  // per-anchor merge across the 4 interleaved gt-subsets (explicit tie-break)
  __syncthreads();
  xb[q][al] = bestbits; xi[q][al] = bidx;
  __syncthreads();
  if (tid < 64) {
    uint32_t bestb = xb[0][tid]; int bi = xi[0][tid];
    #pragma unroll
    for (int qq = 1; qq < 4; ++qq) {
      uint32_t ob = xb[qq][tid]; int og = xi[qq][tid];
      if (ob > bestb || (ob == bestb && og < bi)) { bestb = ob; bi = og; }
    }
    argmax[i] = bi;
    float best = __uint_as_float(bestb);
    int lbl = -1;
    if (best < 0.3f) lbl = 0;
    if (best >= 0.7f) lbl = 1;
    label[i] = lbl;
  }
}

// K3: reduce NPART gkey partitions; force gt-best anchors (last-wins scatter)
__global__ void k_force(const unsigned long long* __restrict__ gkey_part,
                        int* __restrict__ argmax, int* __restrict__ label) {
  __shared__ int ga[G_BOX];
  int tid = threadIdx.x;
  unsigned long long best = gkey_part[tid];
  #pragma unroll
  for (int p = 1; p < NPART; ++p) {
    unsigned long long o = gkey_part[p * G_BOX + tid];
    if (o > best) best = o;
  }
  ga[tid] = (int)(~(uint32_t)(best & 0xffffffffull));
  __syncthreads();
  label[ga[tid]] = 1;
  if (tid == 0) {
    for (int t = 0; t < G_BOX; ++t) argmax[ga[t]] = t;
  }
}

// K4: histogram of priorities over 1024 buckets, per class
__global__ __launch_bounds__(256) void k_hist(const int* __restrict__ label,
                                              uint32_t* __restrict__ hist) {
  int i = blockIdx.x * 256 + threadIdx.x;
  int lbl = label[i];
  if (lbl < 0) return;
  TF2 k = (lbl == 1) ? KPOS : KNEG;
  float p = p_from_bits(rbits(k, (uint32_t)i));
  int b = (int)(p * 1024.0f); if (b > 1023) b = 1023;
  atomicAdd((unsigned int*)&hist[(lbl == 1 ? 0 : 1024) + b], 1u);
}

// K5: find boundary bucket + in-bucket rank for pos and neg
__global__ __launch_bounds__(256) void k_select(const uint32_t* __restrict__ hist,
                                                ScalarBlk* __restrict__ sc) {
  __shared__ uint32_t h[2048];
  for (int t = threadIdx.x; t < 2048; t += 256) h[t] = hist[t];
  __syncthreads();
  if (threadIdx.x != 0) return;
  uint32_t total_pos = 0, total_neg = 0;
  for (int b = 0; b < 1024; ++b) total_pos += h[b];
  for (int b = 0; b < 1024; ++b) total_neg += h[1024 + b];
  int pos_kept = total_pos < (uint32_t)NPOS_TGT ? (int)total_pos : NPOS_TGT;
  int n_neg = NSAMPLE - pos_kept;
  sc->pos_kept = pos_kept;
  if (total_pos <= (uint32_t)NPOS_TGT) {
    sc->do_pos = 0; sc->cutoff[0] = ~0ull;
  } else {
    uint32_t cum = 0; int B = 0;
    for (; B < 1024; ++B) { if (cum + h[B] > (uint32_t)NPOS_TGT) break; cum += h[B]; }
    sc->do_pos = 1; sc->B_pos = B; sc->r_pos = NPOS_TGT - (int)cum;
  }
  if (total_neg <= (uint32_t)n_neg) {
    sc->do_neg = 0; sc->cutoff[1] = ~0ull;
  } else {
    uint32_t cum = 0; int B = 0;
    for (; B < 1024; ++B) { if (cum + h[1024 + B] > (uint32_t)n_neg) break; cum += h[1024 + B]; }
    sc->do_neg = 1; sc->B_neg = B; sc->r_neg = n_neg - (int)cum;
  }
}

// K6: collect boundary-bucket members
__global__ __launch_bounds__(256) void k_collect(const int* __restrict__ label,
                                                 uint64_t* __restrict__ pos_list,
                                                 uint64_t* __restrict__ neg_list,
                                                 uint32_t* __restrict__ counters,
                                                 const ScalarBlk* __restrict__ sc) {
  int i = blockIdx.x * 256 + threadIdx.x;
  int lbl = label[i];
  if (lbl < 0) return;
  if (lbl == 1) {
    if (!sc->do_pos) return;
    float p = p_from_bits(rbits(KPOS, (uint32_t)i));
    int b = (int)(p * 1024.0f); if (b > 1023) b = 1023;
    if (b != sc->B_pos) return;
    uint32_t slot = atomicAdd((unsigned int*)&counters[0], 1u);
    if (slot < POS_CAP) pos_list[slot] = prio_key(p, (uint32_t)i);
  } else {
    if (!sc->do_neg) return;
    float p = p_from_bits(rbits(KNEG, (uint32_t)i));
    int b = (int)(p * 1024.0f); if (b > 1023) b = 1023;
    if (b != sc->B_neg) return;
    uint32_t slot = atomicAdd((unsigned int*)&counters[1], 1u);
    if (slot < NEG_CAP) neg_list[slot] = prio_key(p, (uint32_t)i);
  }
}

// K7: exact r-th smallest key within boundary bucket -> cutoff
__global__ __launch_bounds__(256) void k_cutoff(const uint64_t* __restrict__ pos_list,
                                                const uint64_t* __restrict__ neg_list,
                                                const uint32_t* __restrict__ counters,
                                                ScalarBlk* __restrict__ sc) {
  int cls = blockIdx.x;
  int doit = (cls == 0) ? sc->do_pos : sc->do_neg;
  if (!doit) return;
  const uint64_t* list = (cls == 0) ? pos_list : neg_list;
  int cap = (cls == 0) ? POS_CAP : NEG_CAP;
  int m = (int)counters[cls]; if (m > cap) m = cap;
  int r = (cls == 0) ? sc->r_pos : sc->r_neg;
  for (int j = threadIdx.x; j < m; j += 256) {
    uint64_t kj = list[j];
    int rank = 0;
    for (int t = 0; t < m; ++t) rank += (list[t] < kj) ? 1 : 0;
    if (rank == r) sc->cutoff[cls] = (unsigned long long)kj;
  }
}

// K8: final labels + bbox2loc
__global__ __launch_bounds__(256) void k_final(const float4* __restrict__ anchor,
                                               const float4* __restrict__ bbox,
                                               const int* __restrict__ argmax,
                                               const int* __restrict__ label,
                                               const ScalarBlk* __restrict__ sc,
                                               float* __restrict__ out) {
  #pragma clang fp contract(off)
  int i = blockIdx.x * 256 + threadIdx.x;
  int lbl = label[i];
  if (lbl == 1) {
    float p = p_from_bits(rbits(KPOS, (uint32_t)i));
    if (prio_key(p, (uint32_t)i) >= sc->cutoff[0]) lbl = -1;
  } else if (lbl == 0) {
    float p = p_from_bits(rbits(KNEG, (uint32_t)i));
    if (prio_key(p, (uint32_t)i) >= sc->cutoff[1]) lbl = -1;
  }
  out[K_ANCH * 4 + i] = (float)lbl;

  float4 a = anchor[i];
  float4 b = bbox[argmax[i]];
  const float eps = 1.1920928955078125e-07f;
  float w  = fmaxf(a.z - a.x, eps);
  float h  = fmaxf(a.w - a.y, eps);
  float cx = a.x + 0.5f * (a.z - a.x);
  float cy = a.y + 0.5f * (a.w - a.y);
  float bw = b.z - b.x, bh = b.w - b.y;
  float bcx = b.x + 0.5f * bw, bcy = b.y + 0.5f * bh;
  float dx = (bcx - cx) / w, dy = (bcy - cy) / h;
  float dw = logf(bw / w), dh = logf(bh / h);
  float4 o;
  if (sc->pos_kept > 0) o = make_float4(dx, dy, dw, dh);
  else o = make_float4(0.f, 0.f, 0.f, 0.f);
  ((float4*)out)[i] = o;
}

extern "C" void kernel_launch(void* const* d_in, const int* in_sizes, int n_in,
                              void* d_out, int out_size, void* d_ws, size_t ws_size,
                              hipStream_t stream) {
  const float4* anchor = (const float4*)d_in[0];
  const float4* bbox   = (const float4*)d_in[1];
  char* ws = (char*)d_ws;

  uint32_t* hist     = (uint32_t*)(ws);                   // [0, 8192)
  uint32_t* counters = (uint32_t*)(ws + 8192);            // [8192, 8200)
  unsigned long long* gkey_part = (unsigned long long*)(ws + 16384);  // 32 KB: [16384, 49152)
  ScalarBlk* sc      = (ScalarBlk*)(ws + 49152);
  int* argmax        = (int*)(ws + 65536);                // 512 KB
  int* label         = (int*)(ws + 65536 + 524288);       // 512 KB
  uint64_t* pos_list = (uint64_t*)(ws + 65536 + 1048576);
  uint64_t* neg_list = pos_list + POS_CAP;

  (void)hipMemsetAsync(ws, 0, 49152, stream);  // hist + counters + gkey_part
  k_fused  <<<2048, 256, 0, stream>>>(anchor, bbox, argmax, label, gkey_part);
  k_force  <<<1,    256, 0, stream>>>(gkey_part, argmax, label);
  k_hist   <<<512,  256, 0, stream>>>(label, hist);
  k_select <<<1,    256, 0, stream>>>(hist, sc);
  k_collect<<<512,  256, 0, stream>>>(label, pos_list, neg_list, counters, sc);
  k_cutoff <<<2,    256, 0, stream>>>(pos_list, neg_list, counters, sc);
  k_final  <<<512,  256, 0, stream>>>(anchor, bbox, argmax, label, sc, (float*)d_out);
}

// Round 14
// 132.074 us; speedup vs baseline: 1.0295x; 1.0295x over previous
//
#include <hip/hip_runtime.h>
#include <stdint.h>

#define K_ANCH 131072
#define G_BOX  256
#define NPOS_TGT 128
#define NSAMPLE 256
#define POS_CAP 8192
#define NEG_CAP 32768
#define NPART 16

// ---------------- Threefry-2x32-20 (JAX-compatible) ----------------
struct TF2 { uint32_t a, b; };

__host__ __device__ constexpr uint32_t rotl32(uint32_t v, int d) {
  return (v << d) | (v >> (32 - d));
}

__host__ __device__ constexpr TF2 threefry(uint32_t k0, uint32_t k1,
                                           uint32_t x0, uint32_t x1) {
  const uint32_t ks0 = k0, ks1 = k1, ks2 = k0 ^ k1 ^ 0x1BD11BDAu;
  const int R0[4] = {13, 15, 26, 6};
  const int R1[4] = {17, 29, 16, 24};
  x0 += ks0; x1 += ks1;
  for (int r = 0; r < 4; ++r) { x0 += x1; x1 = rotl32(x1, R0[r]); x1 ^= x0; }
  x0 += ks1; x1 += ks2 + 1u;
  for (int r = 0; r < 4; ++r) { x0 += x1; x1 = rotl32(x1, R1[r]); x1 ^= x0; }
  x0 += ks2; x1 += ks0 + 2u;
  for (int r = 0; r < 4; ++r) { x0 += x1; x1 = rotl32(x1, R0[r]); x1 ^= x0; }
  x0 += ks0; x1 += ks1 + 3u;
  for (int r = 0; r < 4; ++r) { x0 += x1; x1 = rotl32(x1, R1[r]); x1 ^= x0; }
  x0 += ks1; x1 += ks2 + 4u;
  for (int r = 0; r < 4; ++r) { x0 += x1; x1 = rotl32(x1, R0[r]); x1 ^= x0; }
  x0 += ks2; x1 += ks0 + 5u;
  return TF2{x0, x1};
}

constexpr TF2 KPOS = threefry(0u, 42u, 0u, 0u);  // k1 -> p_pos
constexpr TF2 KNEG = threefry(0u, 42u, 0u, 1u);  // k2 -> p_neg

__device__ __forceinline__ uint32_t rbits(TF2 k, uint32_t i) {
  TF2 r = threefry(k.a, k.b, 0u, i);
  return r.a ^ r.b;
}

__device__ __forceinline__ float p_from_bits(uint32_t bits) {
  uint32_t fb = 0x3f800000u | (bits >> 9);
  float f = __uint_as_float(fb) - 1.0f;
  return fmaxf(f, 0.0f);
}

__device__ __forceinline__ uint64_t prio_key(float p, uint32_t idx) {
  return ((uint64_t)__float_as_uint(p) << 32) | (uint64_t)idx;
}

// IoU bitwise-matched to reference (contract off, select-form inter -> always +0).
// area_b computed inline: same expression, single rounding -> bitwise identical.
__device__ __forceinline__ uint32_t iou_bits(float4 a, float area_a, float4 b) {
  #pragma clang fp contract(off)
  float tlx = fmaxf(a.x, b.x), tly = fmaxf(a.y, b.y);
  float brx = fminf(a.z, b.z), bry = fminf(a.w, b.w);
  float w = brx - tlx, h = bry - tly;
  float wh = w * h;
  bool ok = (tlx < brx) && (tly < bry);
  float inter = ok ? wh : 0.0f;
  float area_b = (b.z - b.x) * (b.w - b.y);
  float u = (area_a + area_b) - inter;
  float v = inter / u;                // IEEE div, v >= +0
  return __float_as_uint(v);
}

struct ScalarBlk {
  unsigned long long cutoff[2];
  int B_pos, r_pos, B_neg, r_neg;
  int do_pos, do_neg, pos_kept, pad;
};

// K1 (fused, 512-thread, max-occupancy): block = 64 anchors x 256 gts, 2048 blocks.
// 2 halves of 128 gts: phase1 fills [128 col][65] tile (8 quarters x 16-col
// stripes) keeping per-anchor argmax in registers; phase2 = 128 full-column
// scans. Merge scratch ALIASES the tile (dead after last phase2 barrier).
// LDS = 4 + 33.3 = 37.3 KB -> 4 blocks/CU x 8 waves = 32 waves/CU (max).
__global__ __launch_bounds__(512) void k_fused(const float4* __restrict__ anchor,
                                               const float4* __restrict__ bbox,
                                               int* __restrict__ argmax,
                                               int* __restrict__ label,
                                               unsigned long long* __restrict__ gkey_part) {
  __shared__ float4 gts[G_BOX];             // 4 KB
  __shared__ uint32_t tile[128 * 65];       // 33.28 KB; pad 65 -> conflict-free both ways
  int tid = threadIdx.x;
  int al = tid & 63, q = tid >> 6;          // q in [0,8): 16-col stripe owner
  int abase = blockIdx.x * 64;
  int i = abase + al;

  if (tid < G_BOX) gts[tid] = bbox[tid];
  __syncthreads();

  float4 a = anchor[i];
  float area_a;
  {
    #pragma clang fp contract(off)
    area_a = (a.z - a.x) * (a.w - a.y);
  }
  uint32_t bestbits = 0u; int bidx = 0;     // iou>=+0 -> u32 cmp == f32 cmp

  #pragma unroll
  for (int h = 0; h < 2; ++h) {
    int hg = h * 128;
    // phase1: thread (al,q) computes cols c = q*16+[0,16); g ascending per thread
    #pragma unroll 4
    for (int s = 0; s < 16; ++s) {
      int c = q * 16 + s;
      int g = hg + c;
      float4 b = gts[g];                    // broadcast ds_read_b128 (wave-uniform g)
      uint32_t vb = iou_bits(a, area_a, b);
      if (vb > bestbits) { bestbits = vb; bidx = g; }
      tile[c * 65 + al] = vb;               // lanes consecutive -> conflict-free
    }
    __syncthreads();                        // tile complete
    // phase2: threads 0..127 scan one gt column (ascending a -> first-max = smallest anchor)
    if (tid < 128) {
      int c = tid;
      uint32_t cb = tile[c * 65 + 0]; int ca = 0;
      #pragma unroll 8
      for (int aa = 1; aa < 64; ++aa) {
        uint32_t v = tile[c * 65 + aa];     // stride-65 -> 2 lanes/bank = free
        if (v > cb) { cb = v; ca = aa; }
      }
      unsigned long long key =
          ((unsigned long long)cb << 32) |
          (unsigned long long)(~(uint32_t)(abase + ca));
      atomicMax(&gkey_part[(blockIdx.x & (NPART - 1)) * G_BOX + hg + c], key);
    }
    __syncthreads();                        // scans done before tile overwrite/reuse
  }

  // per-anchor merge across 8 quarters; scratch aliases the (now dead) tile
  uint32_t* xbm = tile;                     // [8][64] best bits
  int* xim = (int*)(tile + 512);            // [8][64] best g
  xbm[tid] = bestbits; xim[tid] = bidx;     // index q*64+al == tid
  __syncthreads();
  if (tid < 64) {
    uint32_t bestb = xbm[tid]; int bi = xim[tid];
    #pragma unroll
    for (int qq = 1; qq < 8; ++qq) {
      uint32_t ob = xbm[qq * 64 + tid]; int og = xim[qq * 64 + tid];
      // quarter g-ranges are non-monotone across qq -> explicit first-index tie-break
      if (ob > bestb || (ob == bestb && og < bi)) { bestb = ob; bi = og; }
    }
    argmax[i] = bi;
    float best = __uint_as_float(bestb);
    int lbl = -1;
    if (best < 0.3f) lbl = 0;
    if (best >= 0.7f) lbl = 1;
    label[i] = lbl;
  }
}

// K3: reduce NPART gkey partitions; force gt-best anchors (last-wins scatter)
__global__ void k_force(const unsigned long long* __restrict__ gkey_part,
                        int* __restrict__ argmax, int* __restrict__ label) {
  __shared__ int ga[G_BOX];
  int tid = threadIdx.x;
  unsigned long long best = gkey_part[tid];
  #pragma unroll
  for (int p = 1; p < NPART; ++p) {
    unsigned long long o = gkey_part[p * G_BOX + tid];
    if (o > best) best = o;
  }
  ga[tid] = (int)(~(uint32_t)(best & 0xffffffffull));
  __syncthreads();
  label[ga[tid]] = 1;
  if (tid == 0) {
    for (int t = 0; t < G_BOX; ++t) argmax[ga[t]] = t;
  }
}

// K4: histogram of priorities over 1024 buckets, per class
__global__ __launch_bounds__(256) void k_hist(const int* __restrict__ label,
                                              uint32_t* __restrict__ hist) {
  int i = blockIdx.x * 256 + threadIdx.x;
  int lbl = label[i];
  if (lbl < 0) return;
  TF2 k = (lbl == 1) ? KPOS : KNEG;
  float p = p_from_bits(rbits(k, (uint32_t)i));
  int b = (int)(p * 1024.0f); if (b > 1023) b = 1023;
  atomicAdd((unsigned int*)&hist[(lbl == 1 ? 0 : 1024) + b], 1u);
}

// K5: find boundary bucket + in-bucket rank for pos and neg
__global__ __launch_bounds__(256) void k_select(const uint32_t* __restrict__ hist,
                                                ScalarBlk* __restrict__ sc) {
  __shared__ uint32_t h[2048];
  for (int t = threadIdx.x; t < 2048; t += 256) h[t] = hist[t];
  __syncthreads();
  if (threadIdx.x != 0) return;
  uint32_t total_pos = 0, total_neg = 0;
  for (int b = 0; b < 1024; ++b) total_pos += h[b];
  for (int b = 0; b < 1024; ++b) total_neg += h[1024 + b];
  int pos_kept = total_pos < (uint32_t)NPOS_TGT ? (int)total_pos : NPOS_TGT;
  int n_neg = NSAMPLE - pos_kept;
  sc->pos_kept = pos_kept;
  if (total_pos <= (uint32_t)NPOS_TGT) {
    sc->do_pos = 0; sc->cutoff[0] = ~0ull;
  } else {
    uint32_t cum = 0; int B = 0;
    for (; B < 1024; ++B) { if (cum + h[B] > (uint32_t)NPOS_TGT) break; cum += h[B]; }
    sc->do_pos = 1; sc->B_pos = B; sc->r_pos = NPOS_TGT - (int)cum;
  }
  if (total_neg <= (uint32_t)n_neg) {
    sc->do_neg = 0; sc->cutoff[1] = ~0ull;
  } else {
    uint32_t cum = 0; int B = 0;
    for (; B < 1024; ++B) { if (cum + h[1024 + B] > (uint32_t)n_neg) break; cum += h[1024 + B]; }
    sc->do_neg = 1; sc->B_neg = B; sc->r_neg = n_neg - (int)cum;
  }
}

// K6: collect boundary-bucket members
__global__ __launch_bounds__(256) void k_collect(const int* __restrict__ label,
                                                 uint64_t* __restrict__ pos_list,
                                                 uint64_t* __restrict__ neg_list,
                                                 uint32_t* __restrict__ counters,
                                                 const ScalarBlk* __restrict__ sc) {
  int i = blockIdx.x * 256 + threadIdx.x;
  int lbl = label[i];
  if (lbl < 0) return;
  if (lbl == 1) {
    if (!sc->do_pos) return;
    float p = p_from_bits(rbits(KPOS, (uint32_t)i));
    int b = (int)(p * 1024.0f); if (b > 1023) b = 1023;
    if (b != sc->B_pos) return;
    uint32_t slot = atomicAdd((unsigned int*)&counters[0], 1u);
    if (slot < POS_CAP) pos_list[slot] = prio_key(p, (uint32_t)i);
  } else {
    if (!sc->do_neg) return;
    float p = p_from_bits(rbits(KNEG, (uint32_t)i));
    int b = (int)(p * 1024.0f); if (b > 1023) b = 1023;
    if (b != sc->B_neg) return;
    uint32_t slot = atomicAdd((unsigned int*)&counters[1], 1u);
    if (slot < NEG_CAP) neg_list[slot] = prio_key(p, (uint32_t)i);
  }
}

// K7: exact r-th smallest key within boundary bucket -> cutoff
__global__ __launch_bounds__(256) void k_cutoff(const uint64_t* __restrict__ pos_list,
                                                const uint64_t* __restrict__ neg_list,
                                                const uint32_t* __restrict__ counters,
                                                ScalarBlk* __restrict__ sc) {
  int cls = blockIdx.x;
  int doit = (cls == 0) ? sc->do_pos : sc->do_neg;
  if (!doit) return;
  const uint64_t* list = (cls == 0) ? pos_list : neg_list;
  int cap = (cls == 0) ? POS_CAP : NEG_CAP;
  int m = (int)counters[cls]; if (m > cap) m = cap;
  int r = (cls == 0) ? sc->r_pos : sc->r_neg;
  for (int j = threadIdx.x; j < m; j += 256) {
    uint64_t kj = list[j];
    int rank = 0;
    for (int t = 0; t < m; ++t) rank += (list[t] < kj) ? 1 : 0;
    if (rank == r) sc->cutoff[cls] = (unsigned long long)kj;
  }
}

// K8: final labels + bbox2loc
__global__ __launch_bounds__(256) void k_final(const float4* __restrict__ anchor,
                                               const float4* __restrict__ bbox,
                                               const int* __restrict__ argmax,
                                               const int* __restrict__ label,
                                               const ScalarBlk* __restrict__ sc,
                                               float* __restrict__ out) {
  #pragma clang fp contract(off)
  int i = blockIdx.x * 256 + threadIdx.x;
  int lbl = label[i];
  if (lbl == 1) {
    float p = p_from_bits(rbits(KPOS, (uint32_t)i));
    if (prio_key(p, (uint32_t)i) >= sc->cutoff[0]) lbl = -1;
  } else if (lbl == 0) {
    float p = p_from_bits(rbits(KNEG, (uint32_t)i));
    if (prio_key(p, (uint32_t)i) >= sc->cutoff[1]) lbl = -1;
  }
  out[K_ANCH * 4 + i] = (float)lbl;

  float4 a = anchor[i];
  float4 b = bbox[argmax[i]];
  const float eps = 1.1920928955078125e-07f;
  float w  = fmaxf(a.z - a.x, eps);
  float h  = fmaxf(a.w - a.y, eps);
  float cx = a.x + 0.5f * (a.z - a.x);
  float cy = a.y + 0.5f * (a.w - a.y);
  float bw = b.z - b.x, bh = b.w - b.y;
  float bcx = b.x + 0.5f * bw, bcy = b.y + 0.5f * bh;
  float dx = (bcx - cx) / w, dy = (bcy - cy) / h;
  float dw = logf(bw / w), dh = logf(bh / h);
  float4 o;
  if (sc->pos_kept > 0) o = make_float4(dx, dy, dw, dh);
  else o = make_float4(0.f, 0.f, 0.f, 0.f);
  ((float4*)out)[i] = o;
}

extern "C" void kernel_launch(void* const* d_in, const int* in_sizes, int n_in,
                              void* d_out, int out_size, void* d_ws, size_t ws_size,
                              hipStream_t stream) {
  const float4* anchor = (const float4*)d_in[0];
  const float4* bbox   = (const float4*)d_in[1];
  char* ws = (char*)d_ws;

  uint32_t* hist     = (uint32_t*)(ws);                   // [0, 8192)
  uint32_t* counters = (uint32_t*)(ws + 8192);            // [8192, 8200)
  unsigned long long* gkey_part = (unsigned long long*)(ws + 16384);  // 32 KB: [16384, 49152)
  ScalarBlk* sc      = (ScalarBlk*)(ws + 49152);
  int* argmax        = (int*)(ws + 65536);                // 512 KB
  int* label         = (int*)(ws + 65536 + 524288);       // 512 KB
  uint64_t* pos_list = (uint64_t*)(ws + 65536 + 1048576);
  uint64_t* neg_list = pos_list + POS_CAP;

  (void)hipMemsetAsync(ws, 0, 49152, stream);  // hist + counters + gkey_part
  k_fused  <<<2048, 512, 0, stream>>>(anchor, bbox, argmax, label, gkey_part);
  k_force  <<<1,    256, 0, stream>>>(gkey_part, argmax, label);
  k_hist   <<<512,  256, 0, stream>>>(label, hist);
  k_select <<<1,    256, 0, stream>>>(hist, sc);
  k_collect<<<512,  256, 0, stream>>>(label, pos_list, neg_list, counters, sc);
  k_cutoff <<<2,    256, 0, stream>>>(pos_list, neg_list, counters, sc);
  k_final  <<<512,  256, 0, stream>>>(anchor, bbox, argmax, label, sc, (float*)d_out);
}

// Round 15
// 130.665 us; speedup vs baseline: 1.0406x; 1.0108x over previous
//
#include <hip/hip_runtime.h>
#include <stdint.h>

#define K_ANCH 131072
#define G_BOX  256
#define NPOS_TGT 128
#define NSAMPLE 256
#define POS_CAP 8192
#define NEG_CAP 32768
#define NPART 16

// ---------------- Threefry-2x32-20 (JAX-compatible) ----------------
struct TF2 { uint32_t a, b; };

__host__ __device__ constexpr uint32_t rotl32(uint32_t v, int d) {
  return (v << d) | (v >> (32 - d));
}

__host__ __device__ constexpr TF2 threefry(uint32_t k0, uint32_t k1,
                                           uint32_t x0, uint32_t x1) {
  const uint32_t ks0 = k0, ks1 = k1, ks2 = k0 ^ k1 ^ 0x1BD11BDAu;
  const int R0[4] = {13, 15, 26, 6};
  const int R1[4] = {17, 29, 16, 24};
  x0 += ks0; x1 += ks1;
  for (int r = 0; r < 4; ++r) { x0 += x1; x1 = rotl32(x1, R0[r]); x1 ^= x0; }
  x0 += ks1; x1 += ks2 + 1u;
  for (int r = 0; r < 4; ++r) { x0 += x1; x1 = rotl32(x1, R1[r]); x1 ^= x0; }
  x0 += ks2; x1 += ks0 + 2u;
  for (int r = 0; r < 4; ++r) { x0 += x1; x1 = rotl32(x1, R0[r]); x1 ^= x0; }
  x0 += ks0; x1 += ks1 + 3u;
  for (int r = 0; r < 4; ++r) { x0 += x1; x1 = rotl32(x1, R1[r]); x1 ^= x0; }
  x0 += ks1; x1 += ks2 + 4u;
  for (int r = 0; r < 4; ++r) { x0 += x1; x1 = rotl32(x1, R0[r]); x1 ^= x0; }
  x0 += ks2; x1 += ks0 + 5u;
  return TF2{x0, x1};
}

constexpr TF2 KPOS = threefry(0u, 42u, 0u, 0u);  // k1 -> p_pos
constexpr TF2 KNEG = threefry(0u, 42u, 0u, 1u);  // k2 -> p_neg

__device__ __forceinline__ uint32_t rbits(TF2 k, uint32_t i) {
  TF2 r = threefry(k.a, k.b, 0u, i);
  return r.a ^ r.b;
}

__device__ __forceinline__ float p_from_bits(uint32_t bits) {
  uint32_t fb = 0x3f800000u | (bits >> 9);
  float f = __uint_as_float(fb) - 1.0f;
  return fmaxf(f, 0.0f);
}

__device__ __forceinline__ uint64_t prio_key(float p, uint32_t idx) {
  return ((uint64_t)__float_as_uint(p) << 32) | (uint64_t)idx;
}

// IoU bitwise-matched to reference (contract off, select-form inter -> always +0).
// area_b computed inline: same expression, single rounding -> bitwise identical.
__device__ __forceinline__ uint32_t iou_bits(float4 a, float area_a, float4 b) {
  #pragma clang fp contract(off)
  float tlx = fmaxf(a.x, b.x), tly = fmaxf(a.y, b.y);
  float brx = fminf(a.z, b.z), bry = fminf(a.w, b.w);
  float w = brx - tlx, h = bry - tly;
  float wh = w * h;
  bool ok = (tlx < brx) && (tly < bry);
  float inter = ok ? wh : 0.0f;
  float area_b = (b.z - b.x) * (b.w - b.y);
  float u = (area_a + area_b) - inter;
  float v = inter / u;                // IEEE div, v >= +0
  return __float_as_uint(v);
}

struct ScalarBlk {
  unsigned long long cutoff[2];
  int B_pos, r_pos, B_neg, r_neg;
  int do_pos, do_neg, pos_kept, pad;
};

// K1 (fused, 512-thread): block = 64 anchors x 256 gts, 2048 blocks.
// __launch_bounds__(512, 8): 8 waves/EU min -> VGPR capped at 64 so 4 blocks/CU
// (32 waves/CU) actually materializes — R12 showed unrolling can balloon VGPR
// to 88 and silently halve occupancy; this pins it.
__global__ __launch_bounds__(512, 8) void k_fused(const float4* __restrict__ anchor,
                                                  const float4* __restrict__ bbox,
                                                  int* __restrict__ argmax,
                                                  int* __restrict__ label,
                                                  unsigned long long* __restrict__ gkey_part) {
  __shared__ float4 gts[G_BOX];             // 4 KB
  __shared__ uint32_t tile[128 * 65];       // 33.28 KB; pad 65 -> conflict-free both ways
  int tid = threadIdx.x;
  int al = tid & 63, q = tid >> 6;          // q in [0,8): 16-col stripe owner
  int abase = blockIdx.x * 64;
  int i = abase + al;

  if (tid < G_BOX) gts[tid] = bbox[tid];
  __syncthreads();

  float4 a = anchor[i];
  float area_a;
  {
    #pragma clang fp contract(off)
    area_a = (a.z - a.x) * (a.w - a.y);
  }
  uint32_t bestbits = 0u; int bidx = 0;     // iou>=+0 -> u32 cmp == f32 cmp

  #pragma unroll
  for (int h = 0; h < 2; ++h) {
    int hg = h * 128;
    // phase1: thread (al,q) computes cols c = q*16+[0,16); g ascending per thread
    #pragma unroll 4
    for (int s = 0; s < 16; ++s) {
      int c = q * 16 + s;
      int g = hg + c;
      float4 b = gts[g];                    // broadcast ds_read_b128 (wave-uniform g)
      uint32_t vb = iou_bits(a, area_a, b);
      if (vb > bestbits) { bestbits = vb; bidx = g; }
      tile[c * 65 + al] = vb;               // lanes consecutive -> conflict-free
    }
    __syncthreads();                        // tile complete
    // phase2: threads 0..127 scan one gt column (ascending a -> first-max = smallest anchor)
    if (tid < 128) {
      int c = tid;
      uint32_t cb = tile[c * 65 + 0]; int ca = 0;
      #pragma unroll 8
      for (int aa = 1; aa < 64; ++aa) {
        uint32_t v = tile[c * 65 + aa];     // stride-65 -> 2 lanes/bank = free
        if (v > cb) { cb = v; ca = aa; }
      }
      unsigned long long key =
          ((unsigned long long)cb << 32) |
          (unsigned long long)(~(uint32_t)(abase + ca));
      atomicMax(&gkey_part[(blockIdx.x & (NPART - 1)) * G_BOX + hg + c], key);
    }
    __syncthreads();                        // scans done before tile overwrite/reuse
  }

  // per-anchor merge across 8 quarters; scratch aliases the (now dead) tile
  uint32_t* xbm = tile;                     // [8][64] best bits
  int* xim = (int*)(tile + 512);            // [8][64] best g
  xbm[tid] = bestbits; xim[tid] = bidx;     // index q*64+al == tid
  __syncthreads();
  if (tid < 64) {
    uint32_t bestb = xbm[tid]; int bi = xim[tid];
    #pragma unroll
    for (int qq = 1; qq < 8; ++qq) {
      uint32_t ob = xbm[qq * 64 + tid]; int og = xim[qq * 64 + tid];
      // quarter g-ranges are non-monotone across qq -> explicit first-index tie-break
      if (ob > bestb || (ob == bestb && og < bi)) { bestb = ob; bi = og; }
    }
    argmax[i] = bi;
    float best = __uint_as_float(bestb);
    int lbl = -1;
    if (best < 0.3f) lbl = 0;
    if (best >= 0.7f) lbl = 1;
    label[i] = lbl;
  }
}

// K3: reduce NPART gkey partitions; force gt-best anchors (last-wins scatter)
__global__ void k_force(const unsigned long long* __restrict__ gkey_part,
                        int* __restrict__ argmax, int* __restrict__ label) {
  __shared__ int ga[G_BOX];
  int tid = threadIdx.x;
  unsigned long long best = gkey_part[tid];
  #pragma unroll
  for (int p = 1; p < NPART; ++p) {
    unsigned long long o = gkey_part[p * G_BOX + tid];
    if (o > best) best = o;
  }
  ga[tid] = (int)(~(uint32_t)(best & 0xffffffffull));
  __syncthreads();
  label[ga[tid]] = 1;
  if (tid == 0) {
    for (int t = 0; t < G_BOX; ++t) argmax[ga[t]] = t;
  }
}

// K4: histogram of priorities over 1024 buckets, per class
__global__ __launch_bounds__(256) void k_hist(const int* __restrict__ label,
                                              uint32_t* __restrict__ hist) {
  int i = blockIdx.x * 256 + threadIdx.x;
  int lbl = label[i];
  if (lbl < 0) return;
  TF2 k = (lbl == 1) ? KPOS : KNEG;
  float p = p_from_bits(rbits(k, (uint32_t)i));
  int b = (int)(p * 1024.0f); if (b > 1023) b = 1023;
  atomicAdd((unsigned int*)&hist[(lbl == 1 ? 0 : 1024) + b], 1u);
}

// K5: find boundary bucket + in-bucket rank for pos and neg
__global__ __launch_bounds__(256) void k_select(const uint32_t* __restrict__ hist,
                                                ScalarBlk* __restrict__ sc) {
  __shared__ uint32_t h[2048];
  for (int t = threadIdx.x; t < 2048; t += 256) h[t] = hist[t];
  __syncthreads();
  if (threadIdx.x != 0) return;
  uint32_t total_pos = 0, total_neg = 0;
  for (int b = 0; b < 1024; ++b) total_pos += h[b];
  for (int b = 0; b < 1024; ++b) total_neg += h[1024 + b];
  int pos_kept = total_pos < (uint32_t)NPOS_TGT ? (int)total_pos : NPOS_TGT;
  int n_neg = NSAMPLE - pos_kept;
  sc->pos_kept = pos_kept;
  if (total_pos <= (uint32_t)NPOS_TGT) {
    sc->do_pos = 0; sc->cutoff[0] = ~0ull;
  } else {
    uint32_t cum = 0; int B = 0;
    for (; B < 1024; ++B) { if (cum + h[B] > (uint32_t)NPOS_TGT) break; cum += h[B]; }
    sc->do_pos = 1; sc->B_pos = B; sc->r_pos = NPOS_TGT - (int)cum;
  }
  if (total_neg <= (uint32_t)n_neg) {
    sc->do_neg = 0; sc->cutoff[1] = ~0ull;
  } else {
    uint32_t cum = 0; int B = 0;
    for (; B < 1024; ++B) { if (cum + h[1024 + B] > (uint32_t)n_neg) break; cum += h[1024 + B]; }
    sc->do_neg = 1; sc->B_neg = B; sc->r_neg = n_neg - (int)cum;
  }
}

// K6: collect boundary-bucket members
__global__ __launch_bounds__(256) void k_collect(const int* __restrict__ label,
                                                 uint64_t* __restrict__ pos_list,
                                                 uint64_t* __restrict__ neg_list,
                                                 uint32_t* __restrict__ counters,
                                                 const ScalarBlk* __restrict__ sc) {
  int i = blockIdx.x * 256 + threadIdx.x;
  int lbl = label[i];
  if (lbl < 0) return;
  if (lbl == 1) {
    if (!sc->do_pos) return;
    float p = p_from_bits(rbits(KPOS, (uint32_t)i));
    int b = (int)(p * 1024.0f); if (b > 1023) b = 1023;
    if (b != sc->B_pos) return;
    uint32_t slot = atomicAdd((unsigned int*)&counters[0], 1u);
    if (slot < POS_CAP) pos_list[slot] = prio_key(p, (uint32_t)i);
  } else {
    if (!sc->do_neg) return;
    float p = p_from_bits(rbits(KNEG, (uint32_t)i));
    int b = (int)(p * 1024.0f); if (b > 1023) b = 1023;
    if (b != sc->B_neg) return;
    uint32_t slot = atomicAdd((unsigned int*)&counters[1], 1u);
    if (slot < NEG_CAP) neg_list[slot] = prio_key(p, (uint32_t)i);
  }
}

// K7: exact r-th smallest key within boundary bucket -> cutoff
__global__ __launch_bounds__(256) void k_cutoff(const uint64_t* __restrict__ pos_list,
                                                const uint64_t* __restrict__ neg_list,
                                                const uint32_t* __restrict__ counters,
                                                ScalarBlk* __restrict__ sc) {
  int cls = blockIdx.x;
  int doit = (cls == 0) ? sc->do_pos : sc->do_neg;
  if (!doit) return;
  const uint64_t* list = (cls == 0) ? pos_list : neg_list;
  int cap = (cls == 0) ? POS_CAP : NEG_CAP;
  int m = (int)counters[cls]; if (m > cap) m = cap;
  int r = (cls == 0) ? sc->r_pos : sc->r_neg;
  for (int j = threadIdx.x; j < m; j += 256) {
    uint64_t kj = list[j];
    int rank = 0;
    for (int t = 0; t < m; ++t) rank += (list[t] < kj) ? 1 : 0;
    if (rank == r) sc->cutoff[cls] = (unsigned long long)kj;
  }
}

// K8: final labels + bbox2loc
__global__ __launch_bounds__(256) void k_final(const float4* __restrict__ anchor,
                                               const float4* __restrict__ bbox,
                                               const int* __restrict__ argmax,
                                               const int* __restrict__ label,
                                               const ScalarBlk* __restrict__ sc,
                                               float* __restrict__ out) {
  #pragma clang fp contract(off)
  int i = blockIdx.x * 256 + threadIdx.x;
  int lbl = label[i];
  if (lbl == 1) {
    float p = p_from_bits(rbits(KPOS, (uint32_t)i));
    if (prio_key(p, (uint32_t)i) >= sc->cutoff[0]) lbl = -1;
  } else if (lbl == 0) {
    float p = p_from_bits(rbits(KNEG, (uint32_t)i));
    if (prio_key(p, (uint32_t)i) >= sc->cutoff[1]) lbl = -1;
  }
  out[K_ANCH * 4 + i] = (float)lbl;

  float4 a = anchor[i];
  float4 b = bbox[argmax[i]];
  const float eps = 1.1920928955078125e-07f;
  float w  = fmaxf(a.z - a.x, eps);
  float h  = fmaxf(a.w - a.y, eps);
  float cx = a.x + 0.5f * (a.z - a.x);
  float cy = a.y + 0.5f * (a.w - a.y);
  float bw = b.z - b.x, bh = b.w - b.y;
  float bcx = b.x + 0.5f * bw, bcy = b.y + 0.5f * bh;
  float dx = (bcx - cx) / w, dy = (bcy - cy) / h;
  float dw = logf(bw / w), dh = logf(bh / h);
  float4 o;
  if (sc->pos_kept > 0) o = make_float4(dx, dy, dw, dh);
  else o = make_float4(0.f, 0.f, 0.f, 0.f);
  ((float4*)out)[i] = o;
}

extern "C" void kernel_launch(void* const* d_in, const int* in_sizes, int n_in,
                              void* d_out, int out_size, void* d_ws, size_t ws_size,
                              hipStream_t stream) {
  const float4* anchor = (const float4*)d_in[0];
  const float4* bbox   = (const float4*)d_in[1];
  char* ws = (char*)d_ws;

  uint32_t* hist     = (uint32_t*)(ws);                   // [0, 8192)
  uint32_t* counters = (uint32_t*)(ws + 8192);            // [8192, 8200)
  unsigned long long* gkey_part = (unsigned long long*)(ws + 16384);  // 32 KB: [16384, 49152)
  ScalarBlk* sc      = (ScalarBlk*)(ws + 49152);
  int* argmax        = (int*)(ws + 65536);                // 512 KB
  int* label         = (int*)(ws + 65536 + 524288);       // 512 KB
  uint64_t* pos_list = (uint64_t*)(ws + 65536 + 1048576);
  uint64_t* neg_list = pos_list + POS_CAP;

  (void)hipMemsetAsync(ws, 0, 49152, stream);  // hist + counters + gkey_part
  k_fused  <<<2048, 512, 0, stream>>>(anchor, bbox, argmax, label, gkey_part);
  k_force  <<<1,    256, 0, stream>>>(gkey_part, argmax, label);
  k_hist   <<<512,  256, 0, stream>>>(label, hist);
  k_select <<<1,    256, 0, stream>>>(hist, sc);
  k_collect<<<512,  256, 0, stream>>>(label, pos_list, neg_list, counters, sc);
  k_cutoff <<<2,    256, 0, stream>>>(pos_list, neg_list, counters, sc);
  k_final  <<<512,  256, 0, stream>>>(anchor, bbox, argmax, label, sc, (float*)d_out);
}